// Round 15
// baseline (183.850 us; speedup 1.0000x reference)
//
#include <hip/hip_runtime.h>

// ---------------- problem constants ----------------
#define B_  2
#define N_  8192
#define I_  32
#define E_  128
#define H_  64
#define BN_ (B_*N_)          // 16384
#define NW_ (N_/64)          // 128 u64 words per (b,i) mask row

typedef unsigned long long u64;

// ---------------- module-scope device state (fully rewritten every launch) -----
__device__ float g_pe  [B_*I_*E_];     // pos_embed
__device__ float g_v1  [B_*I_*H_];     // decode hidden bias, initial
__device__ float g_v2  [B_*I_*H_];     // decode hidden bias, refined
__device__ float g_wd1t[E_*H_];        // Wd1 transposed [e][k]
__device__ float g_u   [H_*BN_];       // u[k][p] (4 MB, k-major -> coalesced)
__device__ u64   g_masks[B_*I_*NW_];   // initial masks as bitwords (64 KB)
__device__ int   g_inter[B_*I_*I_];    // intersection counts (diag = m_sum)

// ---------------- jax threefry2x32, key = key(42) = (0,42) ----------------
__device__ __forceinline__ unsigned rotl_(unsigned x, unsigned n){ return (x<<n)|(x>>(32u-n)); }

__device__ void threefry_42(unsigned x0, unsigned x1, unsigned* r0, unsigned* r1){
  const unsigned ks0 = 0u, ks1 = 42u, ks2 = 0x1BD11BDAu ^ 0u ^ 42u;
  x0 += ks0; x1 += ks1;
  x0+=x1; x1=rotl_(x1,13); x1^=x0;
  x0+=x1; x1=rotl_(x1,15); x1^=x0;
  x0+=x1; x1=rotl_(x1,26); x1^=x0;
  x0+=x1; x1=rotl_(x1, 6); x1^=x0;
  x0+=ks1; x1+=ks2+1u;
  x0+=x1; x1=rotl_(x1,17); x1^=x0;
  x0+=x1; x1=rotl_(x1,29); x1^=x0;
  x0+=x1; x1=rotl_(x1,16); x1^=x0;
  x0+=x1; x1=rotl_(x1,24); x1^=x0;
  x0+=ks2; x1+=ks0+2u;
  x0+=x1; x1=rotl_(x1,13); x1^=x0;
  x0+=x1; x1=rotl_(x1,15); x1^=x0;
  x0+=x1; x1=rotl_(x1,26); x1^=x0;
  x0+=x1; x1=rotl_(x1, 6); x1^=x0;
  x0+=ks0; x1+=ks1+3u;
  x0+=x1; x1=rotl_(x1,17); x1^=x0;
  x0+=x1; x1=rotl_(x1,29); x1^=x0;
  x0+=x1; x1=rotl_(x1,16); x1^=x0;
  x0+=x1; x1=rotl_(x1,24); x1^=x0;
  x0+=ks1; x1+=ks2+4u;
  x0+=x1; x1=rotl_(x1,13); x1^=x0;
  x0+=x1; x1=rotl_(x1,15); x1^=x0;
  x0+=x1; x1=rotl_(x1,26); x1^=x0;
  x0+=x1; x1=rotl_(x1, 6); x1^=x0;
  x0+=ks2; x1+=ks0+5u;
  *r0 = x0; *r1 = x1;
}

// element e of jax.random.uniform(key(42), (2,32,32), 1e-20, 1.0)
// PARTITIONABLE threefry (VERIFIED r7): counter (0,e), bits = out0 ^ out1.
__device__ float jax_uniform_2048(int e){
  unsigned o0, o1;
  threefry_42(0u, (unsigned)e, &o0, &o1);
  unsigned bits = o0 ^ o1;
  float u = __uint_as_float((bits >> 9) | 0x3f800000u) - 1.0f;
  u = u + 1e-20f;
  return fmaxf(1e-20f, u);
}

// ---------------- K0: pos_embed + Wd1^T + v1 (64 blocks, 1 row each) ----------
__global__ void __launch_bounds__(256) prep_kernel(
    const float* __restrict__ pos_coords,
    const float* __restrict__ Wp, const float* __restrict__ bp,
    const float* __restrict__ Wd1,const float* __restrict__ bd1)
{
  __shared__ float t_l [E_*65];      // Wd1^T tile [e][k], pad 65: 33.3 KB
  __shared__ float pe_l[E_];
  const int row = blockIdx.x;        // 0..63 = b*I+i
  const int tid = threadIdx.x;

  for (int idx = tid; idx < H_*E_; idx += 256){
    int k = idx >> 7, e = idx & 127;
    t_l[e*65 + k] = Wd1[idx];
  }
  if (tid < E_){
    const int e = tid;
    float s = pos_coords[row*3+0] * Wp[e*3+0];
    s = fmaf(pos_coords[row*3+1], Wp[e*3+1], s);
    s = fmaf(pos_coords[row*3+2], Wp[e*3+2], s);
    const float pe = s + bp[e];
    g_pe[row*E_ + e] = pe;
    pe_l[e] = pe;
  }
  __syncthreads();

  if (row == 0){
    for (int idx = tid; idx < E_*H_; idx += 256){
      int e = idx >> 6, k = idx & 63;
      g_wd1t[idx] = t_l[e*65 + k];
    }
  }
  if (tid < H_){
    const int k = tid;
    float s = 0.f;
    for (int e = 0; e < 128; ++e)
      s = fmaf(pe_l[e], t_l[e*65 + k], s);
    g_v1[row*H_ + k] = s + bd1[k];
  }
}

// ---------------- K1: FUSED encoder, 1024 threads (16 waves) ------------------
// 256 blocks; phase A: wave w computes pf for e in [w*8,+8);
// phase B: wave w computes u[k] for k in [w*4,+4) via linear e=0..127 dot;
// ballot: wave w handles i in [w*2,+2).
__global__ void __launch_bounds__(1024) enc_kernel(
    const float* __restrict__ points,
    const float* __restrict__ W1, const float* __restrict__ A1,
    const float* __restrict__ B1, const float* __restrict__ W2,
    const float* __restrict__ A2, const float* __restrict__ B2,
    const float* __restrict__ Wd2,const float* __restrict__ bd2,
    float* __restrict__ out_pf)
{
  __shared__ float pf_l[E_*65];      // [e][point]: 33.3 KB
  __shared__ float u_l [64*65];      // [point][k]: 16.6 KB
  const int tid  = threadIdx.x;
  const int w_u  = __builtin_amdgcn_readfirstlane(tid >> 6);  // 0..15
  const int lane = tid & 63;
  const int p0   = blockIdx.x * 64;
  const int p    = p0 + lane;
  const int b    = blockIdx.x >> 7;

  const float x0 = points[p*3+0];
  const float x1 = points[p*3+1];
  const float x2 = points[p*3+2];

  float a1[4];
  #pragma unroll
  for (int r = 0; r < 4; ++r){
    float s = x0 * A1[r*3+0];
    s = fmaf(x1, A1[r*3+1], s);
    s = fmaf(x2, A1[r*3+2], s);
    a1[r] = s;
  }
  float t1[64];
  #pragma unroll
  for (int k = 0; k < 64; ++k){
    float s = x0 * W1[k*3+0];
    s = fmaf(x1, W1[k*3+1], s);
    s = fmaf(x2, W1[k*3+2], s);
    float l = a1[0] * B1[k*4+0];
    l = fmaf(a1[1], B1[k*4+1], l);
    l = fmaf(a1[2], B1[k*4+2], l);
    l = fmaf(a1[3], B1[k*4+3], l);
    t1[k] = fmaxf(fmaf(0.25f, l, s), 0.0f);
  }
  float a2[4];
  #pragma unroll
  for (int r = 0; r < 4; ++r){
    float s = 0.f;
    #pragma unroll
    for (int j = 0; j < 64; ++j) s = fmaf(t1[j], A2[r*64+j], s);
    a2[r] = s;
  }

  // phase A: pf for this wave's 8 e
  const int e0 = w_u * 8;
  for (int ei = 0; ei < 8; ++ei){
    const int e = e0 + ei;                     // wave-uniform -> scalar loads
    float s1 = 0.f;
    #pragma unroll
    for (int j = 0; j < 64; ++j) s1 = fmaf(t1[j], W2[e*64+j], s1);
    float s2 = a2[0] * B2[e*4+0];
    s2 = fmaf(a2[1], B2[e*4+1], s2);
    s2 = fmaf(a2[2], B2[e*4+2], s2);
    s2 = fmaf(a2[3], B2[e*4+3], s2);
    pf_l[e*65 + lane] = fmaf(0.25f, s2, s1);   // conflict-free
  }
  __syncthreads();

  // phase B: u[kbase..kbase+4) via single linear e-chain (order e=0..127)
  const int kbase = w_u * 4;
  float uacc[4];
  #pragma unroll
  for (int kk = 0; kk < 4; ++kk) uacc[kk] = 0.f;
  for (int e = 0; e < 128; ++e){
    const float pf = pf_l[e*65 + lane];        // 2-way aliasing: free
    #pragma unroll
    for (int kk = 0; kk < 4; ++kk)
      uacc[kk] = fmaf(pf, g_wd1t[e*64 + kbase + kk], uacc[kk]);  // s_loads
  }
  #pragma unroll
  for (int kk = 0; kk < 4; ++kk){
    g_u[(size_t)(kbase + kk) * BN_ + p] = uacc[kk];   // coalesced
    u_l[lane*65 + kbase + kk] = uacc[kk];             // conflict-free
  }
  __syncthreads();

  // coalesced pf store
  for (int idx = tid; idx < 64*E_; idx += 1024){
    const int pt = idx >> 7, e = idx & 127;
    out_pf[(size_t)p0 * E_ + idx] = pf_l[e*65 + pt];
  }

  // fused initial decode + ballot: wave w handles i in [w*2, w*2+2)
  const float bd2v = bd2[0];
  float acc[2];
  acc[0] = 0.f; acc[1] = 0.f;
  const int ibase = w_u * 2;
  const float* v = g_v1 + ((b * I_ + ibase) << 6);
  for (int k = 0; k < 64; ++k){
    const float wd2k = Wd2[k];
    const float uk = u_l[lane*65 + k];
    acc[0] = fmaf(wd2k, fmaxf(uk + v[k],      0.0f), acc[0]);
    acc[1] = fmaf(wd2k, fmaxf(uk + v[64 + k], 0.0f), acc[1]);
  }
  #pragma unroll
  for (int ii = 0; ii < 2; ++ii){
    const int i = ibase + ii;
    u64 bal = __ballot(acc[ii] + bd2v > 0.0f);
    if (lane == 0) g_masks[(size_t)(b * I_ + i) * NW_ + (blockIdx.x & 127)] = bal;
  }
}

// ---------------- K2a: inter[r][j] = popcount(m_r & m_j), 64 blocks ----------------
__global__ void __launch_bounds__(256) inter_kernel()
{
  const int r   = blockIdx.x;          // 0..63
  const int b   = r >> 5;
  const int tid = threadIdx.x;
  const int j   = tid >> 3;            // 0..31
  const int ws  = (tid & 7) * 16;      // word segment base
  const u64* mi = g_masks + (size_t)r * NW_;
  const u64* mj = g_masks + (size_t)(b*32 + j) * NW_;
  int s = 0;
  #pragma unroll
  for (int w = 0; w < 16; ++w)
    s += __popcll(mi[ws + w] & mj[ws + w]);
  s += __shfl_xor(s, 1, 64);
  s += __shfl_xor(s, 2, 64);
  s += __shfl_xor(s, 4, 64);
  if ((tid & 7) == 0) g_inter[r*32 + j] = s;
}

// ---------------- K2b: FUSED Gumbel-max + delta + v2 (16 blocks, 4 rows each) --
__global__ void __launch_bounds__(256) sample_kernel(
    const float* __restrict__ pos_coords,
    const float* __restrict__ Wp, const float* __restrict__ bp,
    const float* __restrict__ bd1)
{
  __shared__ int   inter_l[2048];
  __shared__ float delta_l[4*E_];
  __shared__ float nc_l[4][3];
  const int tid  = threadIdx.x;
  const int row0 = blockIdx.x * 4;     // this block's 4 rows

  for (int idx = tid; idx < 2048; idx += 256) inter_l[idx] = g_inter[idx];
  __syncthreads();

  if (tid < 4){
    const int row = row0 + tid;        // = b*32 + i
    const int b = row >> 5;
    const int i = row & 31;
    const int msum_i = inter_l[(b << 10) + (i << 5) + i];   // diag = m_sum
    float best = -INFINITY; int bestj = 0; bool any = false;
    for (int j = 0; j < 32; ++j){
      const int inter = inter_l[(b << 10) + (i << 5) + j];
      const int msum_j = inter_l[(b << 10) + (j << 5) + j];
      const int uni   = msum_i + msum_j - inter;
      // EXACT f32 mimicry of the reference: inter/(union+1e-6) in f32.
      const float iou = (float)inter / ((float)uni + 1e-6f);
      const bool cand = (j != i) && (iou >= 0.1f);
      if (cand){
        any = true;
        const float uu = jax_uniform_2048((row << 5) + j);
        const float g  = -logf(-logf(uu));
        if (g > best){ best = g; bestj = j; }            // first-max like argmax
      }
    }
    nc_l[tid][0] = any ? pos_coords[(b*32 + bestj)*3 + 0] : 0.f;
    nc_l[tid][1] = any ? pos_coords[(b*32 + bestj)*3 + 1] : 0.f;
    nc_l[tid][2] = any ? pos_coords[(b*32 + bestj)*3 + 2] : 0.f;
  }
  __syncthreads();

  for (int idx = tid; idx < 4*E_; idx += 256){
    const int rl = idx >> 7, e = idx & 127;
    float ne = nc_l[rl][0] * Wp[e*3+0];
    ne = fmaf(nc_l[rl][1], Wp[e*3+1], ne);
    ne = fmaf(nc_l[rl][2], Wp[e*3+2], ne);
    ne = ne + bp[e];                                     // == bp when invalid
    delta_l[idx] = g_pe[(row0 + rl)*E_ + e] - ne;
  }
  __syncthreads();

  {
    const int rl = tid >> 6, k = tid & 63;
    float s = 0.f;
    for (int e = 0; e < 128; ++e)
      s = fmaf(delta_l[rl*E_ + e], g_wd1t[e*64 + k], s);
    g_v2[(row0 + rl)*H_ + k] = s + bd1[k];
  }
}

// ---------------- K3: refined decode (256 blocks x 1024 thr, LDS-staged u) ----
__global__ void __launch_bounds__(1024) dec_kernel(
    const float* __restrict__ Wd2, const float* __restrict__ bd2,
    float* __restrict__ out0)
{
  __shared__ float u_l[64*65];       // [point][k]: 16.6 KB
  const int tid  = threadIdx.x;
  const int w_u  = __builtin_amdgcn_readfirstlane(tid >> 6);  // 0..15
  const int lane = tid & 63;
  const int bc   = blockIdx.x;           // 256 blocks
  const int b    = bc >> 7;
  const int nb   = (bc & 127) << 6;
  const int n    = nb + lane;

  // cooperative coalesced u load: g_u[k][p] -> u_l[point][k]
  for (int idx = tid; idx < 64*64; idx += 1024){
    const int k = idx >> 6, pl = idx & 63;   // lanes: pl consecutive
    u_l[pl*65 + k] = g_u[(size_t)k * BN_ + b * N_ + nb + pl];
  }
  __syncthreads();

  // wave w handles i in [w*2, w*2+2); per-acc k-chain preserved
  const float bd2v = bd2[0];
  float acc[2];
  acc[0] = 0.f; acc[1] = 0.f;
  const int ibase = w_u * 2;
  const float* v = g_v2 + ((b * I_ + ibase) << 6);
  for (int k = 0; k < 64; ++k){
    const float wd2k = Wd2[k];
    const float uk = u_l[lane*65 + k];
    acc[0] = fmaf(wd2k, fmaxf(uk + v[k],      0.0f), acc[0]);
    acc[1] = fmaf(wd2k, fmaxf(uk + v[64 + k], 0.0f), acc[1]);
  }
  #pragma unroll
  for (int ii = 0; ii < 2; ++ii){
    const int i = ibase + ii;
    out0[(size_t)(b * I_ + i) * N_ + n] = acc[ii] + bd2v;
  }
}

// ---------------- launch ----------------
extern "C" void kernel_launch(void* const* d_in, const int* in_sizes, int n_in,
                              void* d_out, int out_size, void* d_ws, size_t ws_size,
                              hipStream_t stream)
{
  (void)in_sizes; (void)n_in; (void)out_size; (void)d_ws; (void)ws_size;
  const float* points     = (const float*)d_in[0];
  const float* pos_coords = (const float*)d_in[1];
  const float* W1  = (const float*)d_in[2];
  const float* A1  = (const float*)d_in[3];
  const float* B1  = (const float*)d_in[4];
  const float* W2  = (const float*)d_in[5];
  const float* A2  = (const float*)d_in[6];
  const float* B2  = (const float*)d_in[7];
  const float* Wp  = (const float*)d_in[8];
  const float* bp  = (const float*)d_in[9];
  const float* Wd1 = (const float*)d_in[10];
  const float* bd1 = (const float*)d_in[11];
  const float* Wd2 = (const float*)d_in[12];
  const float* bd2 = (const float*)d_in[13];

  float* out0   = (float*)d_out;                        // refined_logits [B,I,N]
  float* out_pf = out0 + (size_t)B_ * I_ * N_;          // point_feats   [B,N,E]

  prep_kernel<<<64, 256, 0, stream>>>(pos_coords, Wp, bp, Wd1, bd1);
  enc_kernel<<<256, 1024, 0, stream>>>(points, W1, A1, B1, W2, A2, B2,
                                       Wd2, bd2, out_pf);
  inter_kernel<<<64, 256, 0, stream>>>();
  sample_kernel<<<16, 256, 0, stream>>>(pos_coords, Wp, bp, bd1);
  dec_kernel<<<256, 1024, 0, stream>>>(Wd2, bd2, out0);
}

// Round 16
// 158.654 us; speedup vs baseline: 1.1588x; 1.1588x over previous
//
#include <hip/hip_runtime.h>

// ---------------- problem constants ----------------
#define B_  2
#define N_  8192
#define I_  32
#define E_  128
#define H_  64
#define BN_ (B_*N_)          // 16384
#define NW_ (N_/64)          // 128 u64 words per (b,i) mask row

typedef unsigned long long u64;

// ---------------- module-scope device state (fully rewritten every launch) -----
__device__ float g_pe  [B_*I_*E_];     // pos_embed
__device__ float g_v1  [B_*I_*H_];     // decode hidden bias, initial
__device__ float g_v2  [B_*I_*H_];     // decode hidden bias, refined
__device__ float g_wd1t[E_*H_];        // Wd1 transposed [e][k]
__device__ float g_u   [H_*BN_];       // u[k][p] (4 MB, k-major -> coalesced)
__device__ u64   g_masks[B_*I_*NW_];   // initial masks as bitwords (64 KB)
__device__ int   g_inter[B_*I_*I_];    // intersection counts (diag = m_sum)

// ---------------- jax threefry2x32, key = key(42) = (0,42) ----------------
__device__ __forceinline__ unsigned rotl_(unsigned x, unsigned n){ return (x<<n)|(x>>(32u-n)); }

__device__ void threefry_42(unsigned x0, unsigned x1, unsigned* r0, unsigned* r1){
  const unsigned ks0 = 0u, ks1 = 42u, ks2 = 0x1BD11BDAu ^ 0u ^ 42u;
  x0 += ks0; x1 += ks1;
  x0+=x1; x1=rotl_(x1,13); x1^=x0;
  x0+=x1; x1=rotl_(x1,15); x1^=x0;
  x0+=x1; x1=rotl_(x1,26); x1^=x0;
  x0+=x1; x1=rotl_(x1, 6); x1^=x0;
  x0+=ks1; x1+=ks2+1u;
  x0+=x1; x1=rotl_(x1,17); x1^=x0;
  x0+=x1; x1=rotl_(x1,29); x1^=x0;
  x0+=x1; x1=rotl_(x1,16); x1^=x0;
  x0+=x1; x1=rotl_(x1,24); x1^=x0;
  x0+=ks2; x1+=ks0+2u;
  x0+=x1; x1=rotl_(x1,13); x1^=x0;
  x0+=x1; x1=rotl_(x1,15); x1^=x0;
  x0+=x1; x1=rotl_(x1,26); x1^=x0;
  x0+=x1; x1=rotl_(x1, 6); x1^=x0;
  x0+=ks0; x1+=ks1+3u;
  x0+=x1; x1=rotl_(x1,17); x1^=x0;
  x0+=x1; x1=rotl_(x1,29); x1^=x0;
  x0+=x1; x1=rotl_(x1,16); x1^=x0;
  x0+=x1; x1=rotl_(x1,24); x1^=x0;
  x0+=ks1; x1+=ks2+4u;
  x0+=x1; x1=rotl_(x1,13); x1^=x0;
  x0+=x1; x1=rotl_(x1,15); x1^=x0;
  x0+=x1; x1=rotl_(x1,26); x1^=x0;
  x0+=x1; x1=rotl_(x1, 6); x1^=x0;
  x0+=ks2; x1+=ks0+5u;
  *r0 = x0; *r1 = x1;
}

// element e of jax.random.uniform(key(42), (2,32,32), 1e-20, 1.0)
// PARTITIONABLE threefry (VERIFIED r7): counter (0,e), bits = out0 ^ out1.
__device__ float jax_uniform_2048(int e){
  unsigned o0, o1;
  threefry_42(0u, (unsigned)e, &o0, &o1);
  unsigned bits = o0 ^ o1;
  float u = __uint_as_float((bits >> 9) | 0x3f800000u) - 1.0f;
  u = u + 1e-20f;
  return fmaxf(1e-20f, u);
}

// ---------------- K0: pos_embed + Wd1^T + v1 (64 blocks, 1 row each) ----------
__global__ void __launch_bounds__(256) prep_kernel(
    const float* __restrict__ pos_coords,
    const float* __restrict__ Wp, const float* __restrict__ bp,
    const float* __restrict__ Wd1,const float* __restrict__ bd1)
{
  __shared__ float t_l [E_*65];      // Wd1^T tile [e][k], pad 65: 33.3 KB
  __shared__ float pe_l[E_];
  const int row = blockIdx.x;        // 0..63 = b*I+i
  const int tid = threadIdx.x;

  for (int idx = tid; idx < H_*E_; idx += 256){
    int k = idx >> 7, e = idx & 127;
    t_l[e*65 + k] = Wd1[idx];
  }
  if (tid < E_){
    const int e = tid;
    float s = pos_coords[row*3+0] * Wp[e*3+0];
    s = fmaf(pos_coords[row*3+1], Wp[e*3+1], s);
    s = fmaf(pos_coords[row*3+2], Wp[e*3+2], s);
    const float pe = s + bp[e];
    g_pe[row*E_ + e] = pe;
    pe_l[e] = pe;
  }
  __syncthreads();

  if (row == 0){
    for (int idx = tid; idx < E_*H_; idx += 256){
      int e = idx >> 6, k = idx & 63;
      g_wd1t[idx] = t_l[e*65 + k];
    }
  }
  if (tid < H_){
    const int k = tid;
    float s = 0.f;
    for (int e = 0; e < 128; ++e)
      s = fmaf(pe_l[e], t_l[e*65 + k], s);
    g_v1[row*H_ + k] = s + bd1[k];
  }
}

// ---------------- K1: FUSED encoder, 512 threads (8 waves, NO spill) ----------
// 256 blocks; phase A: wave w computes pf for e in [w*16,+16), s1 as 4 ILP chains;
// phase B: wave w computes u[k] for k in [w*8,+8) via linear e=0..127 dot;
// ballot: wave w handles i in [w*4,+4).
__global__ void __launch_bounds__(512) enc_kernel(
    const float* __restrict__ points,
    const float* __restrict__ W1, const float* __restrict__ A1,
    const float* __restrict__ B1, const float* __restrict__ W2,
    const float* __restrict__ A2, const float* __restrict__ B2,
    const float* __restrict__ Wd2,const float* __restrict__ bd2,
    float* __restrict__ out_pf)
{
  __shared__ float pf_l[E_*65];      // [e][point]: 33.3 KB
  __shared__ float u_l [64*65];      // [point][k]: 16.6 KB
  const int tid  = threadIdx.x;
  const int w_u  = __builtin_amdgcn_readfirstlane(tid >> 6);  // 0..7
  const int lane = tid & 63;
  const int p0   = blockIdx.x * 64;
  const int p    = p0 + lane;
  const int b    = blockIdx.x >> 7;

  const float x0 = points[p*3+0];
  const float x1 = points[p*3+1];
  const float x2 = points[p*3+2];

  float a1[4];
  #pragma unroll
  for (int r = 0; r < 4; ++r){
    float s = x0 * A1[r*3+0];
    s = fmaf(x1, A1[r*3+1], s);
    s = fmaf(x2, A1[r*3+2], s);
    a1[r] = s;
  }
  float t1[64];
  #pragma unroll
  for (int k = 0; k < 64; ++k){
    float s = x0 * W1[k*3+0];
    s = fmaf(x1, W1[k*3+1], s);
    s = fmaf(x2, W1[k*3+2], s);
    float l = a1[0] * B1[k*4+0];
    l = fmaf(a1[1], B1[k*4+1], l);
    l = fmaf(a1[2], B1[k*4+2], l);
    l = fmaf(a1[3], B1[k*4+3], l);
    t1[k] = fmaxf(fmaf(0.25f, l, s), 0.0f);
  }
  float a2[4];
  #pragma unroll
  for (int r = 0; r < 4; ++r){
    float s = 0.f;
    #pragma unroll
    for (int j = 0; j < 64; ++j) s = fmaf(t1[j], A2[r*64+j], s);
    a2[r] = s;
  }

  // phase A: pf for this wave's 16 e; s1 as 4 independent 16-chains (ILP)
  const int e0 = w_u * 16;
  #pragma unroll 2
  for (int ei = 0; ei < 16; ++ei){
    const int e = e0 + ei;                     // wave-uniform -> scalar loads
    float sa = 0.f, sb = 0.f, sc = 0.f, sd = 0.f;
    #pragma unroll
    for (int j = 0; j < 16; ++j){
      sa = fmaf(t1[j],      W2[e*64 + j],      sa);
      sb = fmaf(t1[j + 16], W2[e*64 + j + 16], sb);
      sc = fmaf(t1[j + 32], W2[e*64 + j + 32], sc);
      sd = fmaf(t1[j + 48], W2[e*64 + j + 48], sd);
    }
    const float s1 = (sa + sb) + (sc + sd);
    float s2 = a2[0] * B2[e*4+0];
    s2 = fmaf(a2[1], B2[e*4+1], s2);
    s2 = fmaf(a2[2], B2[e*4+2], s2);
    s2 = fmaf(a2[3], B2[e*4+3], s2);
    pf_l[e*65 + lane] = fmaf(0.25f, s2, s1);   // conflict-free
  }
  __syncthreads();

  // phase B: u[kbase..kbase+8) via single linear e-chain (order e=0..127)
  const int kbase = w_u * 8;
  float uacc[8];
  #pragma unroll
  for (int kk = 0; kk < 8; ++kk) uacc[kk] = 0.f;
  for (int e = 0; e < 128; ++e){
    const float pf = pf_l[e*65 + lane];        // 2-way aliasing: free
    #pragma unroll
    for (int kk = 0; kk < 8; ++kk)
      uacc[kk] = fmaf(pf, g_wd1t[e*64 + kbase + kk], uacc[kk]);  // s_loads
  }
  #pragma unroll
  for (int kk = 0; kk < 8; ++kk){
    g_u[(size_t)(kbase + kk) * BN_ + p] = uacc[kk];   // coalesced
    u_l[lane*65 + kbase + kk] = uacc[kk];             // conflict-free
  }
  __syncthreads();

  // coalesced pf store
  for (int idx = tid; idx < 64*E_; idx += 512){
    const int pt = idx >> 7, e = idx & 127;
    out_pf[(size_t)p0 * E_ + idx] = pf_l[e*65 + pt];
  }

  // fused initial decode + ballot: wave w handles i in [w*4, w*4+4)
  const float bd2v = bd2[0];
  float acc[4];
  #pragma unroll
  for (int ii = 0; ii < 4; ++ii) acc[ii] = 0.f;
  const int ibase = w_u * 4;
  const float* v = g_v1 + ((b * I_ + ibase) << 6);
  for (int k = 0; k < 64; ++k){
    const float wd2k = Wd2[k];
    const float uk = u_l[lane*65 + k];
    #pragma unroll
    for (int ii = 0; ii < 4; ++ii)
      acc[ii] = fmaf(wd2k, fmaxf(uk + v[ii*64 + k], 0.0f), acc[ii]);
  }
  #pragma unroll
  for (int ii = 0; ii < 4; ++ii){
    const int i = ibase + ii;
    u64 bal = __ballot(acc[ii] + bd2v > 0.0f);
    if (lane == 0) g_masks[(size_t)(b * I_ + i) * NW_ + (blockIdx.x & 127)] = bal;
  }
}

// ---------------- K2a: inter[r][j] = popcount(m_r & m_j), 64 blocks ----------------
__global__ void __launch_bounds__(256) inter_kernel()
{
  const int r   = blockIdx.x;          // 0..63
  const int b   = r >> 5;
  const int tid = threadIdx.x;
  const int j   = tid >> 3;            // 0..31
  const int ws  = (tid & 7) * 16;      // word segment base
  const u64* mi = g_masks + (size_t)r * NW_;
  const u64* mj = g_masks + (size_t)(b*32 + j) * NW_;
  int s = 0;
  #pragma unroll
  for (int w = 0; w < 16; ++w)
    s += __popcll(mi[ws + w] & mj[ws + w]);
  s += __shfl_xor(s, 1, 64);
  s += __shfl_xor(s, 2, 64);
  s += __shfl_xor(s, 4, 64);
  if ((tid & 7) == 0) g_inter[r*32 + j] = s;
}

// ---------------- K2b: FUSED Gumbel-max + delta + v2 (16 blocks, 4 rows each) --
__global__ void __launch_bounds__(256) sample_kernel(
    const float* __restrict__ pos_coords,
    const float* __restrict__ Wp, const float* __restrict__ bp,
    const float* __restrict__ bd1)
{
  __shared__ int   inter_l[2048];
  __shared__ float delta_l[4*E_];
  __shared__ float nc_l[4][3];
  const int tid  = threadIdx.x;
  const int row0 = blockIdx.x * 4;     // this block's 4 rows

  for (int idx = tid; idx < 2048; idx += 256) inter_l[idx] = g_inter[idx];
  __syncthreads();

  if (tid < 4){
    const int row = row0 + tid;        // = b*32 + i
    const int b = row >> 5;
    const int i = row & 31;
    const int msum_i = inter_l[(b << 10) + (i << 5) + i];   // diag = m_sum
    float best = -INFINITY; int bestj = 0; bool any = false;
    for (int j = 0; j < 32; ++j){
      const int inter = inter_l[(b << 10) + (i << 5) + j];
      const int msum_j = inter_l[(b << 10) + (j << 5) + j];
      const int uni   = msum_i + msum_j - inter;
      // EXACT f32 mimicry of the reference: inter/(union+1e-6) in f32.
      const float iou = (float)inter / ((float)uni + 1e-6f);
      const bool cand = (j != i) && (iou >= 0.1f);
      if (cand){
        any = true;
        const float uu = jax_uniform_2048((row << 5) + j);
        const float g  = -logf(-logf(uu));
        if (g > best){ best = g; bestj = j; }            // first-max like argmax
      }
    }
    nc_l[tid][0] = any ? pos_coords[(b*32 + bestj)*3 + 0] : 0.f;
    nc_l[tid][1] = any ? pos_coords[(b*32 + bestj)*3 + 1] : 0.f;
    nc_l[tid][2] = any ? pos_coords[(b*32 + bestj)*3 + 2] : 0.f;
  }
  __syncthreads();

  for (int idx = tid; idx < 4*E_; idx += 256){
    const int rl = idx >> 7, e = idx & 127;
    float ne = nc_l[rl][0] * Wp[e*3+0];
    ne = fmaf(nc_l[rl][1], Wp[e*3+1], ne);
    ne = fmaf(nc_l[rl][2], Wp[e*3+2], ne);
    ne = ne + bp[e];                                     // == bp when invalid
    delta_l[idx] = g_pe[(row0 + rl)*E_ + e] - ne;
  }
  __syncthreads();

  {
    const int rl = tid >> 6, k = tid & 63;
    float s = 0.f;
    for (int e = 0; e < 128; ++e)
      s = fmaf(delta_l[rl*E_ + e], g_wd1t[e*64 + k], s);
    g_v2[(row0 + rl)*H_ + k] = s + bd1[k];
  }
}

// ---------------- K3: refined decode (256 blocks x 1024 thr, LDS-staged u) ----
__global__ void __launch_bounds__(1024) dec_kernel(
    const float* __restrict__ Wd2, const float* __restrict__ bd2,
    float* __restrict__ out0)
{
  __shared__ float u_l[64*65];       // [point][k]: 16.6 KB
  const int tid  = threadIdx.x;
  const int w_u  = __builtin_amdgcn_readfirstlane(tid >> 6);  // 0..15
  const int lane = tid & 63;
  const int bc   = blockIdx.x;           // 256 blocks
  const int b    = bc >> 7;
  const int nb   = (bc & 127) << 6;
  const int n    = nb + lane;

  for (int idx = tid; idx < 64*64; idx += 1024){
    const int k = idx >> 6, pl = idx & 63;   // lanes: pl consecutive
    u_l[pl*65 + k] = g_u[(size_t)k * BN_ + b * N_ + nb + pl];
  }
  __syncthreads();

  const float bd2v = bd2[0];
  float acc[2];
  acc[0] = 0.f; acc[1] = 0.f;
  const int ibase = w_u * 2;
  const float* v = g_v2 + ((b * I_ + ibase) << 6);
  for (int k = 0; k < 64; ++k){
    const float wd2k = Wd2[k];
    const float uk = u_l[lane*65 + k];
    acc[0] = fmaf(wd2k, fmaxf(uk + v[k],      0.0f), acc[0]);
    acc[1] = fmaf(wd2k, fmaxf(uk + v[64 + k], 0.0f), acc[1]);
  }
  #pragma unroll
  for (int ii = 0; ii < 2; ++ii){
    const int i = ibase + ii;
    out0[(size_t)(b * I_ + i) * N_ + n] = acc[ii] + bd2v;
  }
}

// ---------------- launch ----------------
extern "C" void kernel_launch(void* const* d_in, const int* in_sizes, int n_in,
                              void* d_out, int out_size, void* d_ws, size_t ws_size,
                              hipStream_t stream)
{
  (void)in_sizes; (void)n_in; (void)out_size; (void)d_ws; (void)ws_size;
  const float* points     = (const float*)d_in[0];
  const float* pos_coords = (const float*)d_in[1];
  const float* W1  = (const float*)d_in[2];
  const float* A1  = (const float*)d_in[3];
  const float* B1  = (const float*)d_in[4];
  const float* W2  = (const float*)d_in[5];
  const float* A2  = (const float*)d_in[6];
  const float* B2  = (const float*)d_in[7];
  const float* Wp  = (const float*)d_in[8];
  const float* bp  = (const float*)d_in[9];
  const float* Wd1 = (const float*)d_in[10];
  const float* bd1 = (const float*)d_in[11];
  const float* Wd2 = (const float*)d_in[12];
  const float* bd2 = (const float*)d_in[13];

  float* out0   = (float*)d_out;                        // refined_logits [B,I,N]
  float* out_pf = out0 + (size_t)B_ * I_ * N_;          // point_feats   [B,N,E]

  prep_kernel<<<64, 256, 0, stream>>>(pos_coords, Wp, bp, Wd1, bd1);
  enc_kernel<<<256, 512, 0, stream>>>(points, W1, A1, B1, W2, A2, B2,
                                      Wd2, bd2, out_pf);
  inter_kernel<<<64, 256, 0, stream>>>();
  sample_kernel<<<16, 256, 0, stream>>>(pos_coords, Wp, bp, bd1);
  dec_kernel<<<256, 1024, 0, stream>>>(Wd2, bd2, out0);
}

// Round 17
// 154.027 us; speedup vs baseline: 1.1936x; 1.0300x over previous
//
#include <hip/hip_runtime.h>

// ---------------- problem constants ----------------
#define B_  2
#define N_  8192
#define I_  32
#define E_  128
#define H_  64
#define BN_ (B_*N_)          // 16384
#define NW_ (N_/64)          // 128 u64 words per (b,i) mask row

typedef unsigned long long u64;

// ---------------- module-scope device state (fully rewritten every launch) -----
__device__ float g_pe  [B_*I_*E_];     // pos_embed
__device__ float g_v1  [B_*I_*H_];     // decode hidden bias, initial
__device__ float g_v2  [B_*I_*H_];     // decode hidden bias, refined
__device__ float g_wd1t[E_*H_];        // Wd1 transposed [e][k]
__device__ float g_u   [H_*BN_];       // u[k][p] (4 MB, k-major -> coalesced)
__device__ u64   g_masks[B_*I_*NW_];   // initial masks as bitwords (64 KB)

// ---------------- jax threefry2x32, key = key(42) = (0,42) ----------------
__device__ __forceinline__ unsigned rotl_(unsigned x, unsigned n){ return (x<<n)|(x>>(32u-n)); }

__device__ void threefry_42(unsigned x0, unsigned x1, unsigned* r0, unsigned* r1){
  const unsigned ks0 = 0u, ks1 = 42u, ks2 = 0x1BD11BDAu ^ 0u ^ 42u;
  x0 += ks0; x1 += ks1;
  x0+=x1; x1=rotl_(x1,13); x1^=x0;
  x0+=x1; x1=rotl_(x1,15); x1^=x0;
  x0+=x1; x1=rotl_(x1,26); x1^=x0;
  x0+=x1; x1=rotl_(x1, 6); x1^=x0;
  x0+=ks1; x1+=ks2+1u;
  x0+=x1; x1=rotl_(x1,17); x1^=x0;
  x0+=x1; x1=rotl_(x1,29); x1^=x0;
  x0+=x1; x1=rotl_(x1,16); x1^=x0;
  x0+=x1; x1=rotl_(x1,24); x1^=x0;
  x0+=ks2; x1+=ks0+2u;
  x0+=x1; x1=rotl_(x1,13); x1^=x0;
  x0+=x1; x1=rotl_(x1,15); x1^=x0;
  x0+=x1; x1=rotl_(x1,26); x1^=x0;
  x0+=x1; x1=rotl_(x1, 6); x1^=x0;
  x0+=ks0; x1+=ks1+3u;
  x0+=x1; x1=rotl_(x1,17); x1^=x0;
  x0+=x1; x1=rotl_(x1,29); x1^=x0;
  x0+=x1; x1=rotl_(x1,16); x1^=x0;
  x0+=x1; x1=rotl_(x1,24); x1^=x0;
  x0+=ks1; x1+=ks2+4u;
  x0+=x1; x1=rotl_(x1,13); x1^=x0;
  x0+=x1; x1=rotl_(x1,15); x1^=x0;
  x0+=x1; x1=rotl_(x1,26); x1^=x0;
  x0+=x1; x1=rotl_(x1, 6); x1^=x0;
  x0+=ks2; x1+=ks0+5u;
  *r0 = x0; *r1 = x1;
}

// element e of jax.random.uniform(key(42), (2,32,32), 1e-20, 1.0)
// PARTITIONABLE threefry (VERIFIED r7): counter (0,e), bits = out0 ^ out1.
__device__ float jax_uniform_2048(int e){
  unsigned o0, o1;
  threefry_42(0u, (unsigned)e, &o0, &o1);
  unsigned bits = o0 ^ o1;
  float u = __uint_as_float((bits >> 9) | 0x3f800000u) - 1.0f;
  u = u + 1e-20f;
  return fmaxf(1e-20f, u);
}

// ---------------- K0: pos_embed + Wd1^T + v1 (64 blocks, 1 row each) ----------
__global__ void __launch_bounds__(256) prep_kernel(
    const float* __restrict__ pos_coords,
    const float* __restrict__ Wp, const float* __restrict__ bp,
    const float* __restrict__ Wd1,const float* __restrict__ bd1)
{
  __shared__ float t_l [E_*65];      // Wd1^T tile [e][k], pad 65: 33.3 KB
  __shared__ float pe_l[E_];
  const int row = blockIdx.x;        // 0..63 = b*I+i
  const int tid = threadIdx.x;

  for (int idx = tid; idx < H_*E_; idx += 256){
    int k = idx >> 7, e = idx & 127;
    t_l[e*65 + k] = Wd1[idx];
  }
  if (tid < E_){
    const int e = tid;
    float s = pos_coords[row*3+0] * Wp[e*3+0];
    s = fmaf(pos_coords[row*3+1], Wp[e*3+1], s);
    s = fmaf(pos_coords[row*3+2], Wp[e*3+2], s);
    const float pe = s + bp[e];
    g_pe[row*E_ + e] = pe;
    pe_l[e] = pe;
  }
  __syncthreads();

  if (row == 0){
    for (int idx = tid; idx < E_*H_; idx += 256){
      int e = idx >> 6, k = idx & 63;
      g_wd1t[idx] = t_l[e*65 + k];
    }
  }
  if (tid < H_){
    const int k = tid;
    float s = 0.f;
    for (int e = 0; e < 128; ++e)
      s = fmaf(pe_l[e], t_l[e*65 + k], s);
    g_v1[row*H_ + k] = s + bd1[k];
  }
}

// ---------------- K1: FUSED encoder (R14 shape: measured 41.6 us, no spill) ---
// 256 blocks x 512 threads; phase A: wave w computes pf for e in [w*16,+16);
// phase B: wave w computes u[k] for k in [w*8,+8) via linear e=0..127 dot;
// ballot: wave w handles i in [w*4,+4).
__global__ void __launch_bounds__(512) enc_kernel(
    const float* __restrict__ points,
    const float* __restrict__ W1, const float* __restrict__ A1,
    const float* __restrict__ B1, const float* __restrict__ W2,
    const float* __restrict__ A2, const float* __restrict__ B2,
    const float* __restrict__ Wd2,const float* __restrict__ bd2,
    float* __restrict__ out_pf)
{
  __shared__ float pf_l[E_*65];      // [e][point]: 33.3 KB
  __shared__ float u_l [64*65];      // [point][k]: 16.6 KB
  const int tid  = threadIdx.x;
  const int w_u  = __builtin_amdgcn_readfirstlane(tid >> 6);  // 0..7
  const int lane = tid & 63;
  const int p0   = blockIdx.x * 64;
  const int p    = p0 + lane;
  const int b    = blockIdx.x >> 7;

  const float x0 = points[p*3+0];
  const float x1 = points[p*3+1];
  const float x2 = points[p*3+2];

  float a1[4];
  #pragma unroll
  for (int r = 0; r < 4; ++r){
    float s = x0 * A1[r*3+0];
    s = fmaf(x1, A1[r*3+1], s);
    s = fmaf(x2, A1[r*3+2], s);
    a1[r] = s;
  }
  float t1[64];
  #pragma unroll
  for (int k = 0; k < 64; ++k){
    float s = x0 * W1[k*3+0];
    s = fmaf(x1, W1[k*3+1], s);
    s = fmaf(x2, W1[k*3+2], s);
    float l = a1[0] * B1[k*4+0];
    l = fmaf(a1[1], B1[k*4+1], l);
    l = fmaf(a1[2], B1[k*4+2], l);
    l = fmaf(a1[3], B1[k*4+3], l);
    t1[k] = fmaxf(fmaf(0.25f, l, s), 0.0f);
  }
  float a2[4];
  #pragma unroll
  for (int r = 0; r < 4; ++r){
    float s = 0.f;
    #pragma unroll
    for (int j = 0; j < 64; ++j) s = fmaf(t1[j], A2[r*64+j], s);
    a2[r] = s;
  }

  // phase A: pf for this wave's 16 e (simple serial chain — R14 verbatim)
  const int e0 = w_u * 16;
  for (int ei = 0; ei < 16; ++ei){
    const int e = e0 + ei;                     // wave-uniform -> scalar loads
    float s1 = 0.f;
    #pragma unroll
    for (int j = 0; j < 64; ++j) s1 = fmaf(t1[j], W2[e*64+j], s1);
    float s2 = a2[0] * B2[e*4+0];
    s2 = fmaf(a2[1], B2[e*4+1], s2);
    s2 = fmaf(a2[2], B2[e*4+2], s2);
    s2 = fmaf(a2[3], B2[e*4+3], s2);
    pf_l[e*65 + lane] = fmaf(0.25f, s2, s1);   // conflict-free
  }
  __syncthreads();

  // phase B: u[kbase..kbase+8) via single linear e-chain (order e=0..127)
  const int kbase = w_u * 8;
  float uacc[8];
  #pragma unroll
  for (int kk = 0; kk < 8; ++kk) uacc[kk] = 0.f;
  for (int e = 0; e < 128; ++e){
    const float pf = pf_l[e*65 + lane];        // 2-way aliasing: free
    #pragma unroll
    for (int kk = 0; kk < 8; ++kk)
      uacc[kk] = fmaf(pf, g_wd1t[e*64 + kbase + kk], uacc[kk]);  // s_loads
  }
  #pragma unroll
  for (int kk = 0; kk < 8; ++kk){
    g_u[(size_t)(kbase + kk) * BN_ + p] = uacc[kk];   // coalesced
    u_l[lane*65 + kbase + kk] = uacc[kk];             // conflict-free
  }
  __syncthreads();

  // coalesced pf store
  for (int idx = tid; idx < 64*E_; idx += 512){
    const int pt = idx >> 7, e = idx & 127;
    out_pf[(size_t)p0 * E_ + idx] = pf_l[e*65 + pt];
  }

  // fused initial decode + ballot: wave w handles i in [w*4, w*4+4)
  const float bd2v = bd2[0];
  float acc[4];
  #pragma unroll
  for (int ii = 0; ii < 4; ++ii) acc[ii] = 0.f;
  const int ibase = w_u * 4;
  const float* v = g_v1 + ((b * I_ + ibase) << 6);
  for (int k = 0; k < 64; ++k){
    const float wd2k = Wd2[k];
    const float uk = u_l[lane*65 + k];
    #pragma unroll
    for (int ii = 0; ii < 4; ++ii)
      acc[ii] = fmaf(wd2k, fmaxf(uk + v[ii*64 + k], 0.0f), acc[ii]);
  }
  #pragma unroll
  for (int ii = 0; ii < 4; ++ii){
    const int i = ibase + ii;
    u64 bal = __ballot(acc[ii] + bd2v > 0.0f);
    if (lane == 0) g_masks[(size_t)(b * I_ + i) * NW_ + (blockIdx.x & 127)] = bal;
  }
}

// ---------------- K2: FUSED inter + Gumbel-max + delta + v2 (16 blocks) -------
// block owns 4 rows (all within one b); computes its own popcounts (integer,
// bit-identical to the separate inter kernel), then Gumbel, delta, v2.
__global__ void __launch_bounds__(256) sample_kernel(
    const float* __restrict__ pos_coords,
    const float* __restrict__ Wp, const float* __restrict__ bp,
    const float* __restrict__ bd1)
{
  __shared__ int   inter_l[4*32];    // inter of this block's 4 rows vs all j
  __shared__ int   msum_l[32];       // popcount of each mask row of this b
  __shared__ float delta_l[4*E_];
  __shared__ float nc_l[4][3];
  const int tid  = threadIdx.x;
  const int row0 = blockIdx.x * 4;           // 4 rows, same b (32%4==0)
  const int b    = row0 >> 5;

  // pair popcounts: 128 (rl,j) pairs x 2 threads (64 words each)
  {
    const int pair = tid >> 1;               // 0..127
    const int rl   = pair >> 5;              // 0..3
    const int j    = pair & 31;
    const int half = tid & 1;
    const u64* mi = g_masks + (size_t)(row0 + rl) * NW_ + half*64;
    const u64* mj = g_masks + (size_t)(b*32 + j)  * NW_ + half*64;
    int s = 0;
    #pragma unroll
    for (int w = 0; w < 64; ++w) s += __popcll(mi[w] & mj[w]);
    s += __shfl_xor(s, 1, 64);
    if (half == 0) inter_l[pair] = s;
  }
  // diag popcounts (msum): 32 j x 8 threads (16 words each)
  {
    const int j  = tid >> 3;                 // 0..31
    const int ws = (tid & 7) * 16;
    const u64* mj = g_masks + (size_t)(b*32 + j) * NW_;
    int s = 0;
    #pragma unroll
    for (int w = 0; w < 16; ++w) s += __popcll(mj[ws + w]);
    s += __shfl_xor(s, 1, 64);
    s += __shfl_xor(s, 2, 64);
    s += __shfl_xor(s, 4, 64);
    if ((tid & 7) == 0) msum_l[j] = s;
  }
  __syncthreads();

  if (tid < 4){
    const int row = row0 + tid;              // = b*32 + i
    const int i = row & 31;
    const int msum_i = msum_l[i];
    float best = -INFINITY; int bestj = 0; bool any = false;
    for (int j = 0; j < 32; ++j){
      const int inter = inter_l[(tid << 5) + j];
      const int uni   = msum_i + msum_l[j] - inter;
      // EXACT f32 mimicry of the reference: inter/(union+1e-6) in f32.
      const float iou = (float)inter / ((float)uni + 1e-6f);
      const bool cand = (j != i) && (iou >= 0.1f);
      if (cand){
        any = true;
        const float uu = jax_uniform_2048((row << 5) + j);
        const float g  = -logf(-logf(uu));
        if (g > best){ best = g; bestj = j; }            // first-max like argmax
      }
    }
    nc_l[tid][0] = any ? pos_coords[(b*32 + bestj)*3 + 0] : 0.f;
    nc_l[tid][1] = any ? pos_coords[(b*32 + bestj)*3 + 1] : 0.f;
    nc_l[tid][2] = any ? pos_coords[(b*32 + bestj)*3 + 2] : 0.f;
  }
  __syncthreads();

  for (int idx = tid; idx < 4*E_; idx += 256){
    const int rl = idx >> 7, e = idx & 127;
    float ne = nc_l[rl][0] * Wp[e*3+0];
    ne = fmaf(nc_l[rl][1], Wp[e*3+1], ne);
    ne = fmaf(nc_l[rl][2], Wp[e*3+2], ne);
    ne = ne + bp[e];                                     // == bp when invalid
    delta_l[idx] = g_pe[(row0 + rl)*E_ + e] - ne;
  }
  __syncthreads();

  {
    const int rl = tid >> 6, k = tid & 63;
    float s = 0.f;
    for (int e = 0; e < 128; ++e)
      s = fmaf(delta_l[rl*E_ + e], g_wd1t[e*64 + k], s);
    g_v2[(row0 + rl)*H_ + k] = s + bd1[k];
  }
}

// ---------------- K3: refined decode (256 blocks x 1024 thr, LDS-staged u) ----
__global__ void __launch_bounds__(1024) dec_kernel(
    const float* __restrict__ Wd2, const float* __restrict__ bd2,
    float* __restrict__ out0)
{
  __shared__ float u_l[64*65];       // [point][k]: 16.6 KB
  const int tid  = threadIdx.x;
  const int w_u  = __builtin_amdgcn_readfirstlane(tid >> 6);  // 0..15
  const int lane = tid & 63;
  const int bc   = blockIdx.x;           // 256 blocks
  const int b    = bc >> 7;
  const int nb   = (bc & 127) << 6;
  const int n    = nb + lane;

  for (int idx = tid; idx < 64*64; idx += 1024){
    const int k = idx >> 6, pl = idx & 63;   // lanes: pl consecutive
    u_l[pl*65 + k] = g_u[(size_t)k * BN_ + b * N_ + nb + pl];
  }
  __syncthreads();

  const float bd2v = bd2[0];
  float acc[2];
  acc[0] = 0.f; acc[1] = 0.f;
  const int ibase = w_u * 2;
  const float* v = g_v2 + ((b * I_ + ibase) << 6);
  for (int k = 0; k < 64; ++k){
    const float wd2k = Wd2[k];
    const float uk = u_l[lane*65 + k];
    acc[0] = fmaf(wd2k, fmaxf(uk + v[k],      0.0f), acc[0]);
    acc[1] = fmaf(wd2k, fmaxf(uk + v[64 + k], 0.0f), acc[1]);
  }
  #pragma unroll
  for (int ii = 0; ii < 2; ++ii){
    const int i = ibase + ii;
    out0[(size_t)(b * I_ + i) * N_ + n] = acc[ii] + bd2v;
  }
}

// ---------------- launch ----------------
extern "C" void kernel_launch(void* const* d_in, const int* in_sizes, int n_in,
                              void* d_out, int out_size, void* d_ws, size_t ws_size,
                              hipStream_t stream)
{
  (void)in_sizes; (void)n_in; (void)out_size; (void)d_ws; (void)ws_size;
  const float* points     = (const float*)d_in[0];
  const float* pos_coords = (const float*)d_in[1];
  const float* W1  = (const float*)d_in[2];
  const float* A1  = (const float*)d_in[3];
  const float* B1  = (const float*)d_in[4];
  const float* W2  = (const float*)d_in[5];
  const float* A2  = (const float*)d_in[6];
  const float* B2  = (const float*)d_in[7];
  const float* Wp  = (const float*)d_in[8];
  const float* bp  = (const float*)d_in[9];
  const float* Wd1 = (const float*)d_in[10];
  const float* bd1 = (const float*)d_in[11];
  const float* Wd2 = (const float*)d_in[12];
  const float* bd2 = (const float*)d_in[13];

  float* out0   = (float*)d_out;                        // refined_logits [B,I,N]
  float* out_pf = out0 + (size_t)B_ * I_ * N_;          // point_feats   [B,N,E]

  prep_kernel<<<64, 256, 0, stream>>>(pos_coords, Wp, bp, Wd1, bd1);
  enc_kernel<<<256, 512, 0, stream>>>(points, W1, A1, B1, W2, A2, B2,
                                      Wd2, bd2, out_pf);
  sample_kernel<<<16, 256, 0, stream>>>(pos_coords, Wp, bp, bd1);
  dec_kernel<<<256, 1024, 0, stream>>>(Wd2, bd2, out0);
}

// Round 18
// 144.295 us; speedup vs baseline: 1.2741x; 1.0674x over previous
//
#include <hip/hip_runtime.h>

// ---------------- problem constants ----------------
#define B_  2
#define N_  8192
#define I_  32
#define E_  128
#define H_  64
#define BN_ (B_*N_)          // 16384
#define NW_ (N_/64)          // 128 u64 words per (b,i) mask row

typedef unsigned long long u64;

// ---------------- module-scope device state (fully rewritten every launch) -----
__device__ float g_pe  [B_*I_*E_];     // pos_embed
__device__ float g_v1  [B_*I_*H_];     // decode hidden bias, initial
__device__ float g_v2  [B_*I_*H_];     // decode hidden bias, refined
__device__ float g_wd1t[E_*H_];        // Wd1 transposed [e][k]
__device__ float g_u   [H_*BN_];       // u[k][p] (4 MB, k-major -> coalesced)
__device__ u64   g_masks[B_*I_*NW_];   // initial masks as bitwords (64 KB)

// ---------------- jax threefry2x32, key = key(42) = (0,42) ----------------
__device__ __forceinline__ unsigned rotl_(unsigned x, unsigned n){ return (x<<n)|(x>>(32u-n)); }

__device__ void threefry_42(unsigned x0, unsigned x1, unsigned* r0, unsigned* r1){
  const unsigned ks0 = 0u, ks1 = 42u, ks2 = 0x1BD11BDAu ^ 0u ^ 42u;
  x0 += ks0; x1 += ks1;
  x0+=x1; x1=rotl_(x1,13); x1^=x0;
  x0+=x1; x1=rotl_(x1,15); x1^=x0;
  x0+=x1; x1=rotl_(x1,26); x1^=x0;
  x0+=x1; x1=rotl_(x1, 6); x1^=x0;
  x0+=ks1; x1+=ks2+1u;
  x0+=x1; x1=rotl_(x1,17); x1^=x0;
  x0+=x1; x1=rotl_(x1,29); x1^=x0;
  x0+=x1; x1=rotl_(x1,16); x1^=x0;
  x0+=x1; x1=rotl_(x1,24); x1^=x0;
  x0+=ks2; x1+=ks0+2u;
  x0+=x1; x1=rotl_(x1,13); x1^=x0;
  x0+=x1; x1=rotl_(x1,15); x1^=x0;
  x0+=x1; x1=rotl_(x1,26); x1^=x0;
  x0+=x1; x1=rotl_(x1, 6); x1^=x0;
  x0+=ks0; x1+=ks1+3u;
  x0+=x1; x1=rotl_(x1,17); x1^=x0;
  x0+=x1; x1=rotl_(x1,29); x1^=x0;
  x0+=x1; x1=rotl_(x1,16); x1^=x0;
  x0+=x1; x1=rotl_(x1,24); x1^=x0;
  x0+=ks1; x1+=ks2+4u;
  x0+=x1; x1=rotl_(x1,13); x1^=x0;
  x0+=x1; x1=rotl_(x1,15); x1^=x0;
  x0+=x1; x1=rotl_(x1,26); x1^=x0;
  x0+=x1; x1=rotl_(x1, 6); x1^=x0;
  x0+=ks2; x1+=ks0+5u;
  *r0 = x0; *r1 = x1;
}

// element e of jax.random.uniform(key(42), (2,32,32), 1e-20, 1.0)
// PARTITIONABLE threefry (VERIFIED r7): counter (0,e), bits = out0 ^ out1.
__device__ float jax_uniform_2048(int e){
  unsigned o0, o1;
  threefry_42(0u, (unsigned)e, &o0, &o1);
  unsigned bits = o0 ^ o1;
  float u = __uint_as_float((bits >> 9) | 0x3f800000u) - 1.0f;
  u = u + 1e-20f;
  return fmaxf(1e-20f, u);
}

// ---------------- K0: pos_embed + Wd1^T + v1 (64 blocks, 1 row each) ----------
__global__ void __launch_bounds__(256) prep_kernel(
    const float* __restrict__ pos_coords,
    const float* __restrict__ Wp, const float* __restrict__ bp,
    const float* __restrict__ Wd1,const float* __restrict__ bd1)
{
  __shared__ float t_l [E_*65];      // Wd1^T tile [e][k], pad 65: 33.3 KB
  __shared__ float pe_l[E_];
  const int row = blockIdx.x;        // 0..63 = b*I+i
  const int tid = threadIdx.x;

  for (int idx = tid; idx < H_*E_; idx += 256){
    int k = idx >> 7, e = idx & 127;
    t_l[e*65 + k] = Wd1[idx];
  }
  if (tid < E_){
    const int e = tid;
    float s = pos_coords[row*3+0] * Wp[e*3+0];
    s = fmaf(pos_coords[row*3+1], Wp[e*3+1], s);
    s = fmaf(pos_coords[row*3+2], Wp[e*3+2], s);
    const float pe = s + bp[e];
    g_pe[row*E_ + e] = pe;
    pe_l[e] = pe;
  }
  __syncthreads();

  if (row == 0){
    for (int idx = tid; idx < E_*H_; idx += 256){
      int e = idx >> 6, k = idx & 63;
      g_wd1t[idx] = t_l[e*65 + k];
    }
  }
  if (tid < H_){
    const int k = tid;
    float s = 0.f;
    for (int e = 0; e < 128; ++e)
      s = fmaf(pe_l[e], t_l[e*65 + k], s);
    g_v1[row*H_ + k] = s + bd1[k];
  }
}

// ---------------- K1: FUSED encoder, LDS-staged weights ----------------------
// 256 blocks x 512 threads; phase A: wave w computes pf for e in [w*16,+16)
// reading W2 from LDS (broadcast, no s_load latency); phase B: wave w computes
// u[k] for k in [w*8,+8) via linear e=0..127 dot reading Wd1T from LDS;
// ballot: wave w handles i in [w*4,+4).  LDS total ~112.8 KB (gfx950: 160 KB).
__global__ void __launch_bounds__(512) enc_kernel(
    const float* __restrict__ points,
    const float* __restrict__ W1, const float* __restrict__ A1,
    const float* __restrict__ B1, const float* __restrict__ W2,
    const float* __restrict__ A2, const float* __restrict__ B2,
    const float* __restrict__ Wd2,const float* __restrict__ bd2,
    float* __restrict__ out_pf)
{
  __shared__ float pf_l  [E_*65];    // [e][point]: 33.3 KB
  __shared__ float u_l   [64*65];    // [point][k]: 16.6 KB
  __shared__ float w2_l  [E_*H_];    // W2   [e][j]: 32 KB
  __shared__ float wd1t_l[E_*H_];    // Wd1T [e][k]: 32 KB
  const int tid  = threadIdx.x;
  const int w_u  = __builtin_amdgcn_readfirstlane(tid >> 6);  // 0..7
  const int lane = tid & 63;
  const int p0   = blockIdx.x * 64;
  const int p    = p0 + lane;
  const int b    = blockIdx.x >> 7;

  // cooperative weight staging (coalesced); overlaps with t1 compute below
  for (int idx = tid; idx < E_*H_; idx += 512){
    w2_l[idx]   = W2[idx];
    wd1t_l[idx] = g_wd1t[idx];
  }

  const float x0 = points[p*3+0];
  const float x1 = points[p*3+1];
  const float x2 = points[p*3+2];

  float a1[4];
  #pragma unroll
  for (int r = 0; r < 4; ++r){
    float s = x0 * A1[r*3+0];
    s = fmaf(x1, A1[r*3+1], s);
    s = fmaf(x2, A1[r*3+2], s);
    a1[r] = s;
  }
  float t1[64];
  #pragma unroll
  for (int k = 0; k < 64; ++k){
    float s = x0 * W1[k*3+0];
    s = fmaf(x1, W1[k*3+1], s);
    s = fmaf(x2, W1[k*3+2], s);
    float l = a1[0] * B1[k*4+0];
    l = fmaf(a1[1], B1[k*4+1], l);
    l = fmaf(a1[2], B1[k*4+2], l);
    l = fmaf(a1[3], B1[k*4+3], l);
    t1[k] = fmaxf(fmaf(0.25f, l, s), 0.0f);
  }
  float a2[4];
  #pragma unroll
  for (int r = 0; r < 4; ++r){
    float s = 0.f;
    #pragma unroll
    for (int j = 0; j < 64; ++j) s = fmaf(t1[j], A2[r*64+j], s);
    a2[r] = s;
  }
  __syncthreads();                   // w2_l/wd1t_l ready

  // phase A: pf for this wave's 16 e; W2 row from LDS (broadcast reads)
  const int e0 = w_u * 16;
  for (int ei = 0; ei < 16; ++ei){
    const int e = e0 + ei;
    const float* w2row = w2_l + e*64;          // wave-uniform -> broadcast
    float s1 = 0.f;
    #pragma unroll
    for (int j = 0; j < 64; ++j) s1 = fmaf(t1[j], w2row[j], s1);
    float s2 = a2[0] * B2[e*4+0];
    s2 = fmaf(a2[1], B2[e*4+1], s2);
    s2 = fmaf(a2[2], B2[e*4+2], s2);
    s2 = fmaf(a2[3], B2[e*4+3], s2);
    pf_l[e*65 + lane] = fmaf(0.25f, s2, s1);   // conflict-free
  }
  __syncthreads();

  // phase B: u[kbase..kbase+8) via single linear e-chain (order e=0..127)
  const int kbase = w_u * 8;
  float uacc[8];
  #pragma unroll
  for (int kk = 0; kk < 8; ++kk) uacc[kk] = 0.f;
  for (int e = 0; e < 128; ++e){
    const float pf = pf_l[e*65 + lane];        // 2-way aliasing: free
    const float* wrow = wd1t_l + e*64 + kbase; // wave-uniform -> broadcast
    #pragma unroll
    for (int kk = 0; kk < 8; ++kk)
      uacc[kk] = fmaf(pf, wrow[kk], uacc[kk]);
  }
  #pragma unroll
  for (int kk = 0; kk < 8; ++kk){
    g_u[(size_t)(kbase + kk) * BN_ + p] = uacc[kk];   // coalesced
    u_l[lane*65 + kbase + kk] = uacc[kk];             // conflict-free
  }
  __syncthreads();

  // coalesced pf store
  for (int idx = tid; idx < 64*E_; idx += 512){
    const int pt = idx >> 7, e = idx & 127;
    out_pf[(size_t)p0 * E_ + idx] = pf_l[e*65 + pt];
  }

  // fused initial decode + ballot: wave w handles i in [w*4, w*4+4)
  const float bd2v = bd2[0];
  float acc[4];
  #pragma unroll
  for (int ii = 0; ii < 4; ++ii) acc[ii] = 0.f;
  const int ibase = w_u * 4;
  const float* v = g_v1 + ((b * I_ + ibase) << 6);
  for (int k = 0; k < 64; ++k){
    const float wd2k = Wd2[k];
    const float uk = u_l[lane*65 + k];
    #pragma unroll
    for (int ii = 0; ii < 4; ++ii)
      acc[ii] = fmaf(wd2k, fmaxf(uk + v[ii*64 + k], 0.0f), acc[ii]);
  }
  #pragma unroll
  for (int ii = 0; ii < 4; ++ii){
    const int i = ibase + ii;
    u64 bal = __ballot(acc[ii] + bd2v > 0.0f);
    if (lane == 0) g_masks[(size_t)(b * I_ + i) * NW_ + (blockIdx.x & 127)] = bal;
  }
}

// ---------------- K2: FUSED inter + Gumbel-max + delta + v2 (16 blocks) -------
__global__ void __launch_bounds__(256) sample_kernel(
    const float* __restrict__ pos_coords,
    const float* __restrict__ Wp, const float* __restrict__ bp,
    const float* __restrict__ bd1)
{
  __shared__ int   inter_l[4*32];    // inter of this block's 4 rows vs all j
  __shared__ int   msum_l[32];       // popcount of each mask row of this b
  __shared__ float delta_l[4*E_];
  __shared__ float nc_l[4][3];
  const int tid  = threadIdx.x;
  const int row0 = blockIdx.x * 4;           // 4 rows, same b (32%4==0)
  const int b    = row0 >> 5;

  // pair popcounts: 128 (rl,j) pairs x 2 threads (64 words each)
  {
    const int pair = tid >> 1;               // 0..127
    const int rl   = pair >> 5;              // 0..3
    const int j    = pair & 31;
    const int half = tid & 1;
    const u64* mi = g_masks + (size_t)(row0 + rl) * NW_ + half*64;
    const u64* mj = g_masks + (size_t)(b*32 + j)  * NW_ + half*64;
    int s = 0;
    #pragma unroll
    for (int w = 0; w < 64; ++w) s += __popcll(mi[w] & mj[w]);
    s += __shfl_xor(s, 1, 64);
    if (half == 0) inter_l[pair] = s;
  }
  // diag popcounts (msum): 32 j x 8 threads (16 words each)
  {
    const int j  = tid >> 3;                 // 0..31
    const int ws = (tid & 7) * 16;
    const u64* mj = g_masks + (size_t)(b*32 + j) * NW_;
    int s = 0;
    #pragma unroll
    for (int w = 0; w < 16; ++w) s += __popcll(mj[ws + w]);
    s += __shfl_xor(s, 1, 64);
    s += __shfl_xor(s, 2, 64);
    s += __shfl_xor(s, 4, 64);
    if ((tid & 7) == 0) msum_l[j] = s;
  }
  __syncthreads();

  if (tid < 4){
    const int row = row0 + tid;              // = b*32 + i
    const int i = row & 31;
    const int msum_i = msum_l[i];
    float best = -INFINITY; int bestj = 0; bool any = false;
    for (int j = 0; j < 32; ++j){
      const int inter = inter_l[(tid << 5) + j];
      const int uni   = msum_i + msum_l[j] - inter;
      // EXACT f32 mimicry of the reference: inter/(union+1e-6) in f32.
      const float iou = (float)inter / ((float)uni + 1e-6f);
      const bool cand = (j != i) && (iou >= 0.1f);
      if (cand){
        any = true;
        const float uu = jax_uniform_2048((row << 5) + j);
        const float g  = -logf(-logf(uu));
        if (g > best){ best = g; bestj = j; }            // first-max like argmax
      }
    }
    nc_l[tid][0] = any ? pos_coords[(b*32 + bestj)*3 + 0] : 0.f;
    nc_l[tid][1] = any ? pos_coords[(b*32 + bestj)*3 + 1] : 0.f;
    nc_l[tid][2] = any ? pos_coords[(b*32 + bestj)*3 + 2] : 0.f;
  }
  __syncthreads();

  for (int idx = tid; idx < 4*E_; idx += 256){
    const int rl = idx >> 7, e = idx & 127;
    float ne = nc_l[rl][0] * Wp[e*3+0];
    ne = fmaf(nc_l[rl][1], Wp[e*3+1], ne);
    ne = fmaf(nc_l[rl][2], Wp[e*3+2], ne);
    ne = ne + bp[e];                                     // == bp when invalid
    delta_l[idx] = g_pe[(row0 + rl)*E_ + e] - ne;
  }
  __syncthreads();

  {
    const int rl = tid >> 6, k = tid & 63;
    float s = 0.f;
    for (int e = 0; e < 128; ++e)
      s = fmaf(delta_l[rl*E_ + e], g_wd1t[e*64 + k], s);
    g_v2[(row0 + rl)*H_ + k] = s + bd1[k];
  }
}

// ---------------- K3: refined decode (256 blocks x 1024 thr, LDS-staged u) ----
__global__ void __launch_bounds__(1024) dec_kernel(
    const float* __restrict__ Wd2, const float* __restrict__ bd2,
    float* __restrict__ out0)
{
  __shared__ float u_l[64*65];       // [point][k]: 16.6 KB
  const int tid  = threadIdx.x;
  const int w_u  = __builtin_amdgcn_readfirstlane(tid >> 6);  // 0..15
  const int lane = tid & 63;
  const int bc   = blockIdx.x;           // 256 blocks
  const int b    = bc >> 7;
  const int nb   = (bc & 127) << 6;
  const int n    = nb + lane;

  for (int idx = tid; idx < 64*64; idx += 1024){
    const int k = idx >> 6, pl = idx & 63;   // lanes: pl consecutive
    u_l[pl*65 + k] = g_u[(size_t)k * BN_ + b * N_ + nb + pl];
  }
  __syncthreads();

  const float bd2v = bd2[0];
  float acc[2];
  acc[0] = 0.f; acc[1] = 0.f;
  const int ibase = w_u * 2;
  const float* v = g_v2 + ((b * I_ + ibase) << 6);
  for (int k = 0; k < 64; ++k){
    const float wd2k = Wd2[k];
    const float uk = u_l[lane*65 + k];
    acc[0] = fmaf(wd2k, fmaxf(uk + v[k],      0.0f), acc[0]);
    acc[1] = fmaf(wd2k, fmaxf(uk + v[64 + k], 0.0f), acc[1]);
  }
  #pragma unroll
  for (int ii = 0; ii < 2; ++ii){
    const int i = ibase + ii;
    out0[(size_t)(b * I_ + i) * N_ + n] = acc[ii] + bd2v;
  }
}

// ---------------- launch ----------------
extern "C" void kernel_launch(void* const* d_in, const int* in_sizes, int n_in,
                              void* d_out, int out_size, void* d_ws, size_t ws_size,
                              hipStream_t stream)
{
  (void)in_sizes; (void)n_in; (void)out_size; (void)d_ws; (void)ws_size;
  const float* points     = (const float*)d_in[0];
  const float* pos_coords = (const float*)d_in[1];
  const float* W1  = (const float*)d_in[2];
  const float* A1  = (const float*)d_in[3];
  const float* B1  = (const float*)d_in[4];
  const float* W2  = (const float*)d_in[5];
  const float* A2  = (const float*)d_in[6];
  const float* B2  = (const float*)d_in[7];
  const float* Wp  = (const float*)d_in[8];
  const float* bp  = (const float*)d_in[9];
  const float* Wd1 = (const float*)d_in[10];
  const float* bd1 = (const float*)d_in[11];
  const float* Wd2 = (const float*)d_in[12];
  const float* bd2 = (const float*)d_in[13];

  float* out0   = (float*)d_out;                        // refined_logits [B,I,N]
  float* out_pf = out0 + (size_t)B_ * I_ * N_;          // point_feats   [B,N,E]

  prep_kernel<<<64, 256, 0, stream>>>(pos_coords, Wp, bp, Wd1, bd1);
  enc_kernel<<<256, 512, 0, stream>>>(points, W1, A1, B1, W2, A2, B2,
                                      Wd2, bd2, out_pf);
  sample_kernel<<<16, 256, 0, stream>>>(pos_coords, Wp, bp, bd1);
  dec_kernel<<<256, 1024, 0, stream>>>(Wd2, bd2, out0);
}